// Round 1
// baseline (517.818 us; speedup 1.0000x reference)
//
#include <hip/hip_runtime.h>
#include <hip/hip_bf16.h>
#include <math.h>

typedef __hip_bfloat16 bf16;

#define T_   4
#define C_   64
#define H_   96
#define W_   96
#define CI_  16
#define HW_  9216
#define PS_  7
#define NQX_ 24
#define NQ_  576
#define NC_  441
#define K_   100

__device__ __forceinline__ float ldbf(const void* p, int i) { return __bfloat162float(((const bf16*)p)[i]); }
__device__ __forceinline__ float ldf (const void* p, int i) { return ((const float*)p)[i]; }

// ---------------- dtype detector ----------------
// fp32 data: even 16-bit words are low mantissa bits -> ~uniform exponent field, ~14% "sane".
// bf16 data: even words are real bf16 N(0,1)-scale values -> ~100% sane.
__global__ void detect_k(const unsigned short* __restrict__ v, int* __restrict__ flag)
{
    int tid = threadIdx.x;
    unsigned short w = v[tid * 2];
    int e = (w >> 7) & 0xFF;
    int sane = ((e >= 100 && e <= 140) || ((w & 0x7FFF) == 0)) ? 1 : 0;
#pragma unroll
    for (int off = 1; off < 64; off <<= 1) sane += __shfl_xor(sane, off);
    if (tid == 0) *flag = (sane >= 48) ? 1 : 0;
}

// ---------------- conv1x1 x3 ----------------
template <int ISBF>
__device__ __forceinline__ void conv3_body(const void* vid, const float* w, int t, int pix,
                                           float* B1, float* B2, float* B3)
{
    float a1[CI_], a2[CI_], a3[CI_];
#pragma unroll
    for (int o = 0; o < CI_; o++) { a1[o] = w[3072 + o]; a2[o] = w[3088 + o]; a3[o] = w[3104 + o]; }
    int base = t * C_ * HW_ + pix;
#pragma unroll 4
    for (int c = 0; c < C_; c++) {
        float v = ISBF ? ldbf(vid, base + c * HW_) : ldf(vid, base + c * HW_);
#pragma unroll
        for (int o = 0; o < CI_; o++) {
            a1[o] += v * w[o * 64 + c];
            a2[o] += v * w[1024 + o * 64 + c];
            a3[o] += v * w[2048 + o * 64 + c];
        }
    }
    int ob = t * CI_ * HW_ + pix;
#pragma unroll
    for (int o = 0; o < CI_; o++) {
        B1[ob + o * HW_] = a1[o];
        B2[ob + o * HW_] = a2[o];
        B3[ob + o * HW_] = a3[o];
    }
}

__global__ __launch_bounds__(256) void conv3_k(const void* vid, const void* gw, const void* gb,
                                               const void* tw, const void* tb, const void* pw,
                                               const void* pb, const int* __restrict__ flag,
                                               float* __restrict__ B1, float* __restrict__ B2,
                                               float* __restrict__ B3)
{
    __shared__ float w[3120];
    int tid = threadIdx.x;
    int isbf = *flag;
    if (isbf) {
        for (int i = tid; i < 3120; i += 256) {
            float v;
            if (i < 1024) v = ldbf(gw, i);
            else if (i < 2048) v = ldbf(tw, i - 1024);
            else if (i < 3072) v = ldbf(pw, i - 2048);
            else if (i < 3088) v = ldbf(gb, i - 3072);
            else if (i < 3104) v = ldbf(tb, i - 3088);
            else v = ldbf(pb, i - 3104);
            w[i] = v;
        }
    } else {
        for (int i = tid; i < 3120; i += 256) {
            float v;
            if (i < 1024) v = ldf(gw, i);
            else if (i < 2048) v = ldf(tw, i - 1024);
            else if (i < 3072) v = ldf(pw, i - 2048);
            else if (i < 3088) v = ldf(gb, i - 3072);
            else if (i < 3104) v = ldf(tb, i - 3088);
            else v = ldf(pb, i - 3104);
            w[i] = v;
        }
    }
    __syncthreads();
    int p = blockIdx.x * 256 + tid;   // T_*HW_ = 36864 = 144*256, no bounds check
    int t = p / HW_, pix = p - t * HW_;
    if (isbf) conv3_body<1>(vid, w, t, pix, B1, B2, B3);
    else      conv3_body<0>(vid, w, t, pix, B1, B2, B3);
}

// ---------------- fused attention per (t,q) ----------------
__global__ __launch_bounds__(256) void attn_k(const float* __restrict__ B1,
                                              const float* __restrict__ B2,
                                              const float* __restrict__ B3,
                                              float* __restrict__ ACCb, float* __restrict__ Zb)
{
    __shared__ float reg[CI_ * 729];   // [c][27][27] window of B3, later B2
    __shared__ float sc[NC_];
    __shared__ float qbuf[784];        // query patch; later top-k/softmax state

    int tid = threadIdx.x;
    int q = blockIdx.x, t = blockIdx.y;
    int qy = q / NQX_;
    int qi = qy * 4, qj = (q - qy * NQX_) * 4;
    int r0 = max(0, qi - 10), r1 = min(H_ - 1, qi + 16), nr = r1 - r0 + 1;
    int s0 = max(0, qj - 10), s1 = min(W_ - 1, qj + 16), ns = s1 - s0 + 1;

    const float* B1t = B1 + t * CI_ * HW_;
    const float* B2t = B2 + t * CI_ * HW_;
    const float* B3t = B3 + t * CI_ * HW_;

    // query patch, layout [c][pi][pj]
    for (int d = tid; d < 784; d += 256) {
        int c = d / 49, rem = d - c * 49, pi = rem / 7, pj = rem - pi * 7;
        qbuf[d] = B1t[c * HW_ + min(qi + pi, H_ - 1) * W_ + min(qj + pj, W_ - 1)];
    }
    // B3 window
    int nrs = nr * ns, tot = CI_ * nrs;
    for (int i = tid; i < tot; i += 256) {
        int c = i / nrs, rem = i - c * nrs, rr = rem / ns, ss = rem - rr * ns;
        reg[c * 729 + rr * 27 + ss] = B3t[c * HW_ + (r0 + rr) * W_ + (s0 + ss)];
    }
    __syncthreads();

    // scores: thread handles candidates tid and tid+256
    {
        int k0 = tid;
        int k1 = (tid + 256 < NC_) ? (tid + 256) : (NC_ - 1);
        int a0 = k0 / 21, b0 = k0 - a0 * 21;
        int a1 = k1 / 21, b1 = k1 - a1 * 21;
        int ci0 = min(max(qi + a0 - 10, 0), H_ - 1), cj0 = min(max(qj + b0 - 10, 0), W_ - 1);
        int ci1 = min(max(qi + a1 - 10, 0), H_ - 1), cj1 = min(max(qj + b1 - 10, 0), W_ - 1);
        int rows0[7], cols0[7], rows1[7], cols1[7];
#pragma unroll
        for (int pp = 0; pp < 7; pp++) {
            rows0[pp] = (min(ci0 + pp, H_ - 1) - r0) * 27;
            cols0[pp] =  min(cj0 + pp, W_ - 1) - s0;
            rows1[pp] = (min(ci1 + pp, H_ - 1) - r0) * 27;
            cols1[pp] =  min(cj1 + pp, W_ - 1) - s0;
        }
        float acc0 = 0.f, acc1 = 0.f;
#pragma unroll 1
        for (int c = 0; c < CI_; c++) {
            const float* qc = qbuf + c * 49;
            const float* rc = reg + c * 729;
#pragma unroll
            for (int pi = 0; pi < 7; pi++) {
                const float* qr = qc + pi * 7;
                const float* rA = rc + rows0[pi];
                const float* rB = rc + rows1[pi];
#pragma unroll
                for (int pj = 0; pj < 7; pj++) {
                    float qv = qr[pj];
                    acc0 += qv * rA[cols0[pj]];
                    acc1 += qv * rB[cols1[pj]];
                }
            }
        }
        sc[k0] = acc0;
        if (tid + 256 < NC_) sc[tid + 256] = acc1;
    }
    __syncthreads();

    float* topv = qbuf;                  // [100]
    int*   topk = (int*)(qbuf + 128);    // [100]
    float* yiw  = qbuf + 256;            // [100]
    int*   prow = (int*)(qbuf + 384);    // [100]
    int*   pcol = (int*)(qbuf + 512);    // [100]

    if (tid < 64) {
        // iterative top-100; tie-break = lowest index (matches jax.lax.top_k;
        // border-clipped duplicate candidates have bitwise-equal scores)
        for (int i = 0; i < K_; i++) {
            float bv = -INFINITY; int bk = NC_;
#pragma unroll
            for (int j = 0; j < 7; j++) {
                int k = j * 64 + tid;
                if (k < NC_) {
                    float v = sc[k];
                    if (v > bv) { bv = v; bk = k; }   // strict > keeps lowest k per lane
                }
            }
#pragma unroll
            for (int off = 1; off < 64; off <<= 1) {
                float ov = __shfl_xor(bv, off);
                int   ok = __shfl_xor(bk, off);
                if (ov > bv || (ov == bv && ok < bk)) { bv = ov; bk = ok; }
            }
            topv[i] = bv;
            topk[i] = bk;
            sc[bk] = -INFINITY;          // all lanes, same addr/value
        }
        // softmax over the 100 selected (topv[0] is the max)
        float m = topv[0];
        float ca = (tid < K_) ? expf((topv[tid] - m) * 10.0f) : 0.f;
        float cb = (tid + 64 < K_) ? expf((topv[tid + 64] - m) * 10.0f) : 0.f;
        float ssum = ca + cb;
#pragma unroll
        for (int off = 1; off < 64; off <<= 1) ssum += __shfl_xor(ssum, off);
        float inv = 1.0f / ssum;
        if (tid < K_) {
            yiw[tid] = ca * inv;
            int bk = topk[tid], a = bk / 21, b = bk - a * 21;
            prow[tid] = min(max(qi + a - 10, 0), H_ - 1);
            pcol[tid] = min(max(qj + b - 10, 0), W_ - 1);
        }
        if (tid + 64 < K_) {
            yiw[tid + 64] = cb * inv;
            int bk = topk[tid + 64], a = bk / 21, b = bk - a * 21;
            prow[tid + 64] = min(max(qi + a - 10, 0), H_ - 1);
            pcol[tid + 64] = min(max(qj + b - 10, 0), W_ - 1);
        }
    } else {
        // waves 1-3: concurrently reload window from B2 (wave0 doesn't touch reg)
        int tt = tid - 64;
        for (int i = tt; i < tot; i += 192) {
            int c = i / nrs, rem = i - c * nrs, rr = rem / ns, ss = rem - rr * ns;
            reg[c * 729 + rr * 27 + ss] = B2t[c * HW_ + (r0 + rr) * W_ + (s0 + ss)];
        }
    }
    __syncthreads();

    // weighted patch sum + overlap-add scatter
    for (int d = tid; d < 784; d += 256) {
        int c = d / 49, rem = d - c * 49, pi = rem / 7, pj = rem - pi * 7;
        const float* rc = reg + c * 729;
        float s = 0.f;
#pragma unroll 4
        for (int k = 0; k < K_; k++) {
            int rr = min(prow[k] + pi, H_ - 1) - r0;
            int cc = min(pcol[k] + pj, W_ - 1) - s0;
            s += yiw[k] * rc[rr * 27 + cc];
        }
        int orow = min(qi + pi, H_ - 1), ocol = min(qj + pj, W_ - 1);
        atomicAdd(&ACCb[(t * CI_ + c) * HW_ + orow * W_ + ocol], s);
        if (t == 0 && c == 0) atomicAdd(&Zb[orow * W_ + ocol], 1.0f);
    }
}

// ---------------- final: y = ACC/Z, conv1x1 + residual ----------------
template <int ISBF>
__device__ __forceinline__ void out_body(const void* vid, const float* w, const float* ACCb,
                                         const float* Zb, void* out, int t, int pix)
{
    float zv = Zb[pix];
    float y[CI_];
    int ab = t * CI_ * HW_ + pix;
#pragma unroll
    for (int ci = 0; ci < CI_; ci++) y[ci] = ACCb[ab + ci * HW_] / zv;
    int vb = t * C_ * HW_ + pix;
#pragma unroll 4
    for (int co = 0; co < C_; co++) {
        float s = w[1024 + co];
#pragma unroll
        for (int ci = 0; ci < CI_; ci++) s += w[co * CI_ + ci] * y[ci];
        float vv = ISBF ? ldbf(vid, vb + co * HW_) : ldf(vid, vb + co * HW_);
        float r = vv + s;
        if (ISBF) ((bf16*)out)[vb + co * HW_] = __float2bfloat16(r);
        else      ((float*)out)[vb + co * HW_] = r;
    }
}

__global__ __launch_bounds__(256) void out_k(const void* vid, const void* Ww, const void* Wb,
                                             const int* __restrict__ flag,
                                             const float* __restrict__ ACCb,
                                             const float* __restrict__ Zb, void* out)
{
    __shared__ float w[1088];
    int tid = threadIdx.x;
    int isbf = *flag;
    if (isbf) { for (int i = tid; i < 1088; i += 256) w[i] = (i < 1024) ? ldbf(Ww, i) : ldbf(Wb, i - 1024); }
    else      { for (int i = tid; i < 1088; i += 256) w[i] = (i < 1024) ? ldf (Ww, i) : ldf (Wb, i - 1024); }
    __syncthreads();
    int p = blockIdx.x * 256 + tid;
    int t = p / HW_, pix = p - t * HW_;
    if (isbf) out_body<1>(vid, w, ACCb, Zb, out, t, pix);
    else      out_body<0>(vid, w, ACCb, Zb, out, t, pix);
}

extern "C" void kernel_launch(void* const* d_in, const int* in_sizes, int n_in,
                              void* d_out, int out_size, void* d_ws, size_t ws_size,
                              hipStream_t stream)
{
    // ws float layout:
    //   B1 @ 0, B2 @ 589824, B3 @ 1179648, ACC @ 1769472, Z @ 2359296, flag @ 2368512
    float* ws  = (float*)d_ws;
    float* B1  = ws;
    float* B2  = ws + 589824;
    float* B3  = ws + 1179648;
    float* ACCb = ws + 1769472;
    float* Zb  = ws + 2359296;
    int* flag  = (int*)(ws + 2368512);

    hipMemsetAsync(ACCb, 0, (589824 + 9216) * sizeof(float), stream);
    detect_k<<<dim3(1), dim3(64), 0, stream>>>((const unsigned short*)d_in[0], flag);
    conv3_k<<<dim3(144), dim3(256), 0, stream>>>(d_in[0], d_in[1], d_in[2], d_in[3], d_in[4],
                                                 d_in[5], d_in[6], flag, B1, B2, B3);
    attn_k<<<dim3(NQ_, T_), dim3(256), 0, stream>>>(B1, B2, B3, ACCb, Zb);
    out_k<<<dim3(144), dim3(256), 0, stream>>>(d_in[0], d_in[7], d_in[8], flag, ACCb, Zb, d_out);
}

// Round 2
// 455.499 us; speedup vs baseline: 1.1368x; 1.1368x over previous
//
#include <hip/hip_runtime.h>
#include <hip/hip_bf16.h>
#include <math.h>

typedef __hip_bfloat16 bf16;

#define T_   4
#define C_   64
#define H_   96
#define W_   96
#define CI_  16
#define HW_  9216
#define NQX_ 24
#define NQ_  576
#define NC_  441
#define K_   100

__device__ __forceinline__ float ldbf(const void* p, int i) { return __bfloat162float(((const bf16*)p)[i]); }
__device__ __forceinline__ float ldf (const void* p, int i) { return ((const float*)p)[i]; }

// per-block dtype vote (fp32 low-mantissa words decode to "insane" bf16 exponents)
__device__ __forceinline__ int detect_flag(const void* vid, int tid, int* sflag) {
    if (tid < 64) {
        unsigned short w = ((const unsigned short*)vid)[tid * 2];
        int e = (w >> 7) & 0xFF;
        int sane = ((e >= 100 && e <= 140) || ((w & 0x7FFF) == 0)) ? 1 : 0;
#pragma unroll
        for (int off = 1; off < 64; off <<= 1) sane += __shfl_xor(sane, off);
        if (tid == 0) *sflag = (sane >= 48) ? 1 : 0;
    }
    __syncthreads();
    return *sflag;
}

// ---------------- conv1x1 x3 ----------------
template <int ISBF>
__device__ __forceinline__ void conv3_body(const void* vid, const float* w, int t, int pix,
                                           float* B1, float* B2, float* B3)
{
    float a1[CI_], a2[CI_], a3[CI_];
#pragma unroll
    for (int o = 0; o < CI_; o++) { a1[o] = w[3072 + o]; a2[o] = w[3088 + o]; a3[o] = w[3104 + o]; }
    int base = t * C_ * HW_ + pix;
#pragma unroll 4
    for (int c = 0; c < C_; c++) {
        float v = ISBF ? ldbf(vid, base + c * HW_) : ldf(vid, base + c * HW_);
#pragma unroll
        for (int o = 0; o < CI_; o++) {
            a1[o] += v * w[o * 64 + c];
            a2[o] += v * w[1024 + o * 64 + c];
            a3[o] += v * w[2048 + o * 64 + c];
        }
    }
    int ob = t * CI_ * HW_ + pix;
#pragma unroll
    for (int o = 0; o < CI_; o++) {
        B1[ob + o * HW_] = a1[o];
        B2[ob + o * HW_] = a2[o];
        B3[ob + o * HW_] = a3[o];
    }
}

__global__ __launch_bounds__(128) void conv3_k(const void* vid, const void* gw, const void* gb,
                                               const void* tw, const void* tb, const void* pw,
                                               const void* pb,
                                               float* __restrict__ B1, float* __restrict__ B2,
                                               float* __restrict__ B3)
{
    __shared__ float w[3120];
    __shared__ int sflag;
    int tid = threadIdx.x;
    int isbf = detect_flag(vid, tid, &sflag);
    if (isbf) {
        for (int i = tid; i < 3120; i += 128) {
            float v;
            if (i < 1024) v = ldbf(gw, i);
            else if (i < 2048) v = ldbf(tw, i - 1024);
            else if (i < 3072) v = ldbf(pw, i - 2048);
            else if (i < 3088) v = ldbf(gb, i - 3072);
            else if (i < 3104) v = ldbf(tb, i - 3088);
            else v = ldbf(pb, i - 3104);
            w[i] = v;
        }
    } else {
        for (int i = tid; i < 3120; i += 128) {
            float v;
            if (i < 1024) v = ldf(gw, i);
            else if (i < 2048) v = ldf(tw, i - 1024);
            else if (i < 3072) v = ldf(pw, i - 2048);
            else if (i < 3088) v = ldf(gb, i - 3072);
            else if (i < 3104) v = ldf(tb, i - 3088);
            else v = ldf(pb, i - 3104);
            w[i] = v;
        }
    }
    __syncthreads();
    int p = blockIdx.x * 128 + tid;   // 288*128 = 36864 exactly
    int t = p / HW_, pix = p - t * HW_;
    if (isbf) conv3_body<1>(vid, w, t, pix, B1, B2, B3);
    else      conv3_body<0>(vid, w, t, pix, B1, B2, B3);
}

// ---------------- fused attention per (t,q) ----------------
// Regularized: virtual 27x27 window W[u][v] = B3[clip(qi-10+u)][clip(qj-10+v)]
// (upper clips compose; lower-border candidates are bitwise duplicates of the
//  threshold candidate -> computed once on the effective rectangle, then copied)
__global__ __launch_bounds__(256, 3) void attn_k(const float* __restrict__ B1,
                                                 const float* __restrict__ B2,
                                                 const float* __restrict__ B3,
                                                 float* __restrict__ ACCb, float* __restrict__ Zb)
{
    __shared__ float Wb_[CI_ * 729];  // virtual window (B3, later B2)  46656 B
    __shared__ float sc[NC_];         // scores                          1764 B
    __shared__ float qz[784];         // query patch, later z-accum      3136 B
    __shared__ float yiw[K_];         // softmax weights                  400 B
    __shared__ int   pab[K_];         // packed effective (a',b')         400 B

    int tid = threadIdx.x;
    int q = blockIdx.x, t = blockIdx.y;
    int qy = q / NQX_;
    int qi = qy * 4, qj = (q - qy * NQX_) * 4;
    int alo = max(0, 10 - qi), ahi = min(20, 105 - qi);
    int blo = max(0, 10 - qj), bhi = min(20, 105 - qj);

    const float* B1t = B1 + t * CI_ * HW_;
    const float* B2t = B2 + t * CI_ * HW_;
    const float* B3t = B3 + t * CI_ * HW_;

    for (int i = tid; i < NC_; i += 256) sc[i] = 0.f;
    for (int d = tid; d < 784; d += 256) {
        int c = d / 49, rem = d - c * 49, pi = rem / 7, pj = rem - pi * 7;
        qz[d] = B1t[c * HW_ + min(qi + pi, H_ - 1) * W_ + min(qj + pj, W_ - 1)];
    }
    for (int i = tid; i < CI_ * 729; i += 256) {
        int c = i / 729, rem = i - c * 729, r = rem / 27, s = rem - r * 27;
        int sr = min(max(qi - 10 + r, 0), H_ - 1);
        int ss = min(max(qj - 10 + s, 0), W_ - 1);
        Wb_[i] = B3t[c * HW_ + sr * W_ + ss];
    }
    __syncthreads();

    // ---- score phase: lane = (a, b-group of 7); wave handles 4 channels ----
    int w = tid >> 6, lane = tid & 63;
    int a = lane / 3, bg = lane - a * 3, b0 = bg * 7;
    if (lane < 63) {
        float acc[7] = {0.f, 0.f, 0.f, 0.f, 0.f, 0.f, 0.f};
#pragma unroll 1
        for (int cc = 0; cc < 4; cc++) {
            int c = w * 4 + cc;
            const float* qc = qz + c * 49;
            const float* wc = Wb_ + c * 729 + b0;
#pragma unroll 1
            for (int pi = 0; pi < 7; pi++) {
                const float* row = wc + (a + pi) * 27;
                float L[13];
#pragma unroll
                for (int j = 0; j < 13; j++) L[j] = row[j];
#pragma unroll
                for (int pj = 0; pj < 7; pj++) {
                    float qv = qc[pi * 7 + pj];
#pragma unroll
                    for (int bb = 0; bb < 7; bb++) acc[bb] += qv * L[bb + pj];
                }
            }
        }
#pragma unroll
        for (int bb = 0; bb < 7; bb++) atomicAdd(&sc[a * 21 + b0 + bb], acc[bb]);
    }
    __syncthreads();

    // ---- fixup border duplicates (bitwise copies of effective candidate) ----
    for (int k = tid; k < NC_; k += 256) {
        int aa = k / 21, bb = k - aa * 21;
        int ae = min(max(aa, alo), ahi), be = min(max(bb, blo), bhi);
        if (ae != aa || be != bb) sc[k] = sc[ae * 21 + be];  // reads only effective cells
    }
    for (int d = tid; d < 784; d += 256) qz[d] = 0.f;  // qbuf dead -> z-accum
    __syncthreads();

    // ---- wave0: register-resident top-100 + softmax; waves 1-3: restage B2 ----
    if (w == 0) {
        float v[7];
        int kbase;
        if (lane < 63) {
            kbase = a * 21 + b0;
#pragma unroll
            for (int j = 0; j < 7; j++) v[j] = sc[kbase + j];
        } else {
            kbase = 100000;
#pragma unroll
            for (int j = 0; j < 7; j++) v[j] = -INFINITY;
        }
        float va = 0.f, vb = 0.f, m = 0.f;
        int ka = 0, kb = 0;
        for (int i = 0; i < K_; i++) {
            float bv = v[0]; int bj = 0;
#pragma unroll
            for (int j = 1; j < 7; j++) if (v[j] > bv) { bv = v[j]; bj = j; }
            int bk = kbase + bj;
#pragma unroll
            for (int off = 1; off < 64; off <<= 1) {
                float ov = __shfl_xor(bv, off);
                int   ok = __shfl_xor(bk, off);
                if (ov > bv || (ov == bv && ok < bk)) { bv = ov; bk = ok; }
            }
            int d = bk - kbase;
#pragma unroll
            for (int j = 0; j < 7; j++) if (d == j) v[j] = -INFINITY;  // no dynamic reg index
            if (i == 0) m = bv;
            if (i < 64) { if (lane == i) { va = bv; ka = bk; } }
            else        { if (lane == i - 64) { vb = bv; kb = bk; } }
        }
        float ca = expf((va - m) * 10.0f);
        float cb = (lane < K_ - 64) ? expf((vb - m) * 10.0f) : 0.f;
        float ssum = ca + cb;
#pragma unroll
        for (int off = 1; off < 64; off <<= 1) ssum += __shfl_xor(ssum, off);
        float inv = 1.0f / ssum;
        {
            int aa = ka / 21, bb = ka - aa * 21;
            yiw[lane] = ca * inv;
            pab[lane] = (min(max(aa, alo), ahi) << 5) | min(max(bb, blo), bhi);
        }
        if (lane < K_ - 64) {
            int aa = kb / 21, bb = kb - aa * 21;
            yiw[lane + 64] = cb * inv;
            pab[lane + 64] = (min(max(aa, alo), ahi) << 5) | min(max(bb, blo), bhi);
        }
    } else {
        for (int i = tid - 64; i < CI_ * 729; i += 192) {
            int c = i / 729, rem = i - c * 729, r = rem / 27, s = rem - r * 27;
            int sr = min(max(qi - 10 + r, 0), H_ - 1);
            int ss = min(max(qj - 10 + s, 0), W_ - 1);
            Wb_[i] = B2t[c * HW_ + sr * W_ + ss];
        }
    }
    __syncthreads();

    // ---- weighted patch sum: task=(c,pi), 4-way (task-half x k-half) split ----
    {
        int task = (w & 1) * 64 + lane;
        int kbeg = (w >> 1) * 50;
        if (task < 112) {
            int c = task / 7, pi = task - c * 7;
            const float* wc = Wb_ + c * 729;
            float z[7] = {0.f, 0.f, 0.f, 0.f, 0.f, 0.f, 0.f};
#pragma unroll 2
            for (int k = kbeg; k < kbeg + 50; k++) {
                float y = yiw[k];
                int p = pab[k];
                const float* row = wc + ((p >> 5) + pi) * 27 + (p & 31);
#pragma unroll
                for (int pj = 0; pj < 7; pj++) z[pj] += y * row[pj];
            }
#pragma unroll
            for (int pj = 0; pj < 7; pj++) atomicAdd(&qz[c * 49 + pi * 7 + pj], z[pj]);
        }
    }
    __syncthreads();

    // ---- overlap-add scatter ----
    for (int d = tid; d < 784; d += 256) {
        int c = d / 49, rem = d - c * 49, pi = rem / 7, pj = rem - pi * 7;
        int orow = min(qi + pi, H_ - 1), ocol = min(qj + pj, W_ - 1);
        atomicAdd(&ACCb[(t * CI_ + c) * HW_ + orow * W_ + ocol], qz[d]);
        if (t == 0 && c == 0) atomicAdd(&Zb[orow * W_ + ocol], 1.0f);
    }
}

// ---------------- final: y = ACC/Z, conv1x1 + residual ----------------
template <int ISBF>
__device__ __forceinline__ void out_body(const void* vid, const float* w, const float* ACCb,
                                         const float* Zb, void* out, int t, int pix)
{
    float zv = Zb[pix];
    float y[CI_];
    int ab = t * CI_ * HW_ + pix;
#pragma unroll
    for (int ci = 0; ci < CI_; ci++) y[ci] = ACCb[ab + ci * HW_] / zv;
    int vb = t * C_ * HW_ + pix;
#pragma unroll 4
    for (int co = 0; co < C_; co++) {
        float s = w[1024 + co];
#pragma unroll
        for (int ci = 0; ci < CI_; ci++) s += w[co * CI_ + ci] * y[ci];
        float vv = ISBF ? ldbf(vid, vb + co * HW_) : ldf(vid, vb + co * HW_);
        float r = vv + s;
        if (ISBF) ((bf16*)out)[vb + co * HW_] = __float2bfloat16(r);
        else      ((float*)out)[vb + co * HW_] = r;
    }
}

__global__ __launch_bounds__(128) void out_k(const void* vid, const void* Ww, const void* Wb,
                                             const float* __restrict__ ACCb,
                                             const float* __restrict__ Zb, void* out)
{
    __shared__ float w[1088];
    __shared__ int sflag;
    int tid = threadIdx.x;
    int isbf = detect_flag(vid, tid, &sflag);
    if (isbf) { for (int i = tid; i < 1088; i += 128) w[i] = (i < 1024) ? ldbf(Ww, i) : ldbf(Wb, i - 1024); }
    else      { for (int i = tid; i < 1088; i += 128) w[i] = (i < 1024) ? ldf (Ww, i) : ldf (Wb, i - 1024); }
    __syncthreads();
    int p = blockIdx.x * 128 + tid;
    int t = p / HW_, pix = p - t * HW_;
    if (isbf) out_body<1>(vid, w, ACCb, Zb, out, t, pix);
    else      out_body<0>(vid, w, ACCb, Zb, out, t, pix);
}

extern "C" void kernel_launch(void* const* d_in, const int* in_sizes, int n_in,
                              void* d_out, int out_size, void* d_ws, size_t ws_size,
                              hipStream_t stream)
{
    // ws float layout: B1 @0, B2 @589824, B3 @1179648, ACC @1769472, Z @2359296
    float* ws   = (float*)d_ws;
    float* B1   = ws;
    float* B2   = ws + 589824;
    float* B3   = ws + 1179648;
    float* ACCb = ws + 1769472;
    float* Zb   = ws + 2359296;

    hipMemsetAsync(ACCb, 0, (589824 + 9216) * sizeof(float), stream);
    conv3_k<<<dim3(288), dim3(128), 0, stream>>>(d_in[0], d_in[1], d_in[2], d_in[3], d_in[4],
                                                 d_in[5], d_in[6], B1, B2, B3);
    attn_k<<<dim3(NQ_, T_), dim3(256), 0, stream>>>(B1, B2, B3, ACCb, Zb);
    out_k<<<dim3(288), dim3(128), 0, stream>>>(d_in[0], d_in[7], d_in[8], ACCb, Zb, d_out);
}

// Round 3
// 427.124 us; speedup vs baseline: 1.2123x; 1.0664x over previous
//
#include <hip/hip_runtime.h>
#include <hip/hip_bf16.h>
#include <hip/hip_fp16.h>
#include <math.h>

typedef __hip_bfloat16 bf16;
typedef __attribute__((ext_vector_type(8))) short short8;
typedef __attribute__((ext_vector_type(4))) float float4v;

#define T_   4
#define C_   64
#define H_   96
#define W_   96
#define CI_  16
#define HW_  9216
#define NQX_ 24
#define NQ_  576
#define NC_  441
#define K_   100

__device__ __forceinline__ float ldbf(const void* p, int i) { return __bfloat162float(((const bf16*)p)[i]); }
__device__ __forceinline__ float ldf (const void* p, int i) { return ((const float*)p)[i]; }

__device__ __forceinline__ unsigned short f2bf(float x) {
    union { float f; unsigned u; } a; a.f = x;
    unsigned r = a.u + 0x7FFF + ((a.u >> 16) & 1);
    return (unsigned short)(r >> 16);
}
__device__ __forceinline__ float bf2f(unsigned short s) {
    union { unsigned u; float f; } a; a.u = ((unsigned)s) << 16;
    return a.f;
}

// per-block dtype vote (fp32 low-mantissa words decode to "insane" bf16 exponents)
__device__ __forceinline__ int detect_flag(const void* vid, int tid, int* sflag) {
    if (tid < 64) {
        unsigned short w = ((const unsigned short*)vid)[tid * 2];
        int e = (w >> 7) & 0xFF;
        int sane = ((e >= 100 && e <= 140) || ((w & 0x7FFF) == 0)) ? 1 : 0;
#pragma unroll
        for (int off = 1; off < 64; off <<= 1) sane += __shfl_xor(sane, off);
        if (tid == 0) *sflag = (sane >= 48) ? 1 : 0;
    }
    __syncthreads();
    return *sflag;
}

// ---------------- conv1x1 x3 ----------------
template <int ISBF>
__device__ __forceinline__ void conv3_body(const void* vid, const float* w, int t, int pix,
                                           float* B1, float* B2, float* B3)
{
    float a1[CI_], a2[CI_], a3[CI_];
#pragma unroll
    for (int o = 0; o < CI_; o++) { a1[o] = w[3072 + o]; a2[o] = w[3088 + o]; a3[o] = w[3104 + o]; }
    int base = t * C_ * HW_ + pix;
#pragma unroll 16
    for (int c = 0; c < C_; c++) {
        float v = ISBF ? ldbf(vid, base + c * HW_) : ldf(vid, base + c * HW_);
#pragma unroll
        for (int o = 0; o < CI_; o++) {
            a1[o] += v * w[o * 64 + c];
            a2[o] += v * w[1024 + o * 64 + c];
            a3[o] += v * w[2048 + o * 64 + c];
        }
    }
    int ob = t * CI_ * HW_ + pix;
#pragma unroll
    for (int o = 0; o < CI_; o++) {
        B1[ob + o * HW_] = a1[o];
        B2[ob + o * HW_] = a2[o];
        B3[ob + o * HW_] = a3[o];
    }
}

__global__ __launch_bounds__(128) void conv3_k(const void* vid, const void* gw, const void* gb,
                                               const void* tw, const void* tb, const void* pw,
                                               const void* pb,
                                               float* __restrict__ B1, float* __restrict__ B2,
                                               float* __restrict__ B3)
{
    __shared__ float w[3120];
    __shared__ int sflag;
    int tid = threadIdx.x;
    int isbf = detect_flag(vid, tid, &sflag);
    if (isbf) {
        for (int i = tid; i < 3120; i += 128) {
            float v;
            if (i < 1024) v = ldbf(gw, i);
            else if (i < 2048) v = ldbf(tw, i - 1024);
            else if (i < 3072) v = ldbf(pw, i - 2048);
            else if (i < 3088) v = ldbf(gb, i - 3072);
            else if (i < 3104) v = ldbf(tb, i - 3088);
            else v = ldbf(pb, i - 3104);
            w[i] = v;
        }
    } else {
        for (int i = tid; i < 3120; i += 128) {
            float v;
            if (i < 1024) v = ldf(gw, i);
            else if (i < 2048) v = ldf(tw, i - 1024);
            else if (i < 3072) v = ldf(pw, i - 2048);
            else if (i < 3088) v = ldf(gb, i - 3072);
            else if (i < 3104) v = ldf(tb, i - 3088);
            else v = ldf(pb, i - 3104);
            w[i] = v;
        }
    }
    __syncthreads();
    int p = blockIdx.x * 128 + tid;   // 288*128 = 36864 exactly
    int t = p / HW_, pix = p - t * HW_;
    if (isbf) conv3_body<1>(vid, w, t, pix, B1, B2, B3);
    else      conv3_body<0>(vid, w, t, pix, B1, B2, B3);
}

// ---------------- fused attention: one block = 2 horizontally-adjacent queries ----------------
// Score GEMM: C[s'][n] = sum_{c,pi} qv[n][c,pi,pj(n)] * W[r+pi][s'][c]
//   n = q*8 + pj (pj=7 slot zeroed), K = pi*16+c (padded to 128), M = 16 window cols.
//   score[q][r][b] = sum_pj C[b+4q+pj][q*8+pj]  (shift-add epilogue)
// bf16 2-term split (h+l) for ~1e-5 relative accuracy; border duplicates fixed up
// by bitwise copy from the effective rectangle (preserves jax top_k tie semantics).
__global__ __launch_bounds__(256) void attn_k(const float* __restrict__ B1,
                                              const float* __restrict__ B2,
                                              const float* __restrict__ B3,
                                              float* __restrict__ ACCb, float* __restrict__ Zb)
{
    __shared__ __align__(16) char SM[64976];
    short*   Wh  = (short*)SM;                  // [28][32][16] bf16-hi   28672 B
    short*   Wl  = (short*)(SM + 28672);        // [28][32][16] bf16-lo   28672 B
    float*   Sc  = (float*)(SM + 57344);        // [2][441]                3528 B
    float*   Cb  = (float*)(SM + 60880);        // [4 waves][16 n][16 s']  4096 B
    float*   yiw = (float*)(SM + 60880);        // overlay: [2][100]
    int*     pab = (int*)(SM + 61680);          //          [2][100]
    __half2* Wp  = (__half2*)SM;                // PV overlay: [27][32][8] h2

    int tid = threadIdx.x;
    int p = blockIdx.x, t = blockIdx.y;
    int qy = p / 12, qxp = p - qy * 12;
    int qi = qy * 4, qj = qxp * 8;
    int alo = max(0, 10 - qi), ahi = min(20, 105 - qi);

    const float* B1t = B1 + t * CI_ * HW_;
    const float* B2t = B2 + t * CI_ * HW_;
    const float* B3t = B3 + t * CI_ * HW_;

    int lane = tid & 63, w = tid >> 6;
    int nn = lane & 15, qsel = nn >> 3, pjn = nn & 7;
    int koff = (lane >> 4) * 8;

    // ---- B-fragments (query patches) -> registers, bf16 h/l split ----
    short8 Bh[4], Bl[4];
    {
        int qjq = qj + 4 * qsel;
#pragma unroll
        for (int s = 0; s < 4; s++) {
#pragma unroll
            for (int j = 0; j < 8; j++) {
                int kk = s * 32 + koff + j;
                int pi = kk >> 4, c = kk & 15;
                float val = 0.f;
                if (pjn < 7 && pi < 7)
                    val = B1t[c * HW_ + min(qi + pi, 95) * 96 + min(qjq + pjn, 95)];
                unsigned short h = f2bf(val);
                Bh[s][j] = (short)h;
                Bl[s][j] = (short)f2bf(val - bf2f(h));
            }
        }
    }

    // ---- stage B3 virtual window [row][col][c] as bf16 h/l planes ----
    for (int pos = tid; pos < 864; pos += 256) {
        int row = pos >> 5, col = pos & 31;
        int vr = min(max(qi - 10 + row, 0), 95);
        int vc = min(max(qj - 10 + col, 0), 95);
        const float* src = B3t + vr * 96 + vc;
        short hs[16], ls[16];
#pragma unroll
        for (int c = 0; c < 16; c++) {
            float f = src[c * HW_];
            unsigned short h = f2bf(f);
            hs[c] = (short)h;
            ls[c] = (short)f2bf(f - bf2f(h));
        }
        *(int4*)(Wh + pos * 16)     = *(int4*)(hs);
        *(int4*)(Wh + pos * 16 + 8) = *(int4*)(hs + 8);
        *(int4*)(Wl + pos * 16)     = *(int4*)(ls);
        *(int4*)(Wl + pos * 16 + 8) = *(int4*)(ls + 8);
    }
    for (int i = tid; i < 512; i += 256) { Wh[13824 + i] = 0; Wl[13824 + i] = 0; }  // pad row 27
    __syncthreads();

    // ---- score phase: wave handles r = w, w+4, ... ; wave-private C bounce ----
    {
        float* Cw = Cb + w * 256;   // [n][16 s'-in-tile]
        for (int r = w; r < 21; r += 4) {
            float psum = 0.f;
            int v = (lane >= 21) ? 1 : 0;
            int b = lane - v * 21;
#pragma unroll
            for (int st = 0; st < 2; st++) {
                float4v acc = {0.f, 0.f, 0.f, 0.f};
#pragma unroll
                for (int s = 0; s < 4; s++) {
                    int arow = r + 2 * s + (lane >> 5);
                    int aoff = (arow * 32 + st * 16 + nn) * 16 + ((lane >> 4) & 1) * 8;
                    short8 Ah = *(const short8*)(Wh + aoff);
                    short8 Al = *(const short8*)(Wl + aoff);
                    acc = __builtin_amdgcn_mfma_f32_16x16x32_bf16(Ah, Bh[s], acc, 0, 0, 0);
                    acc = __builtin_amdgcn_mfma_f32_16x16x32_bf16(Al, Bh[s], acc, 0, 0, 0);
                    acc = __builtin_amdgcn_mfma_f32_16x16x32_bf16(Ah, Bl[s], acc, 0, 0, 0);
                }
                // C frag: col n = lane&15, rows quad*4+reg -> [n][16] layout, b128 store
                *(float4v*)(Cw + nn * 16 + (lane >> 4) * 4) = acc;
                if (lane < 42) {
#pragma unroll
                    for (int pj = 0; pj < 7; pj++) {
                        int sp = b + 4 * v + pj;
                        if ((sp >> 4) == st) psum += Cw[(8 * v + pj) * 16 + (sp & 15)];
                    }
                }
            }
            if (lane < 42) Sc[v * 441 + r * 21 + b] = psum;
        }
    }
    __syncthreads();

    // ---- border-duplicate fixup (bitwise copy -> exact tie semantics) ----
    for (int idx = tid; idx < 882; idx += 256) {
        int v = idx / 441, k = idx - v * 441;
        int a = k / 21, b = k - a * 21;
        int qq = qj + 4 * v;
        int blo = max(0, 10 - qq), bhi = min(20, 105 - qq);
        int ae = min(max(a, alo), ahi), be = min(max(b, blo), bhi);
        if (ae != a || be != b) Sc[v * 441 + k] = Sc[v * 441 + ae * 21 + be];
    }
    __syncthreads();

    // ---- waves 0,1: top-100 + softmax per query; waves 2,3: restage B2 as f16 ----
    if (w < 2) {
        const float* S = Sc + w * 441;
        float v7[7]; int kbase;
        if (lane < 63) {
            kbase = lane * 7;
#pragma unroll
            for (int j = 0; j < 7; j++) v7[j] = S[kbase + j];
        } else {
            kbase = 1 << 20;
#pragma unroll
            for (int j = 0; j < 7; j++) v7[j] = -INFINITY;
        }
        float va = 0.f, vb2 = 0.f, m = 0.f;
        int ka = 0, kb = 0;
        for (int i = 0; i < K_; i++) {
            float bv = v7[0]; int bj = 0;
#pragma unroll
            for (int j = 1; j < 7; j++) if (v7[j] > bv) { bv = v7[j]; bj = j; }
            int bk = kbase + bj;
#pragma unroll
            for (int off = 1; off < 64; off <<= 1) {
                float ov = __shfl_xor(bv, off);
                int ok = __shfl_xor(bk, off);
                if (ov > bv || (ov == bv && ok < bk)) { bv = ov; bk = ok; }
            }
            int d = bk - kbase;
#pragma unroll
            for (int j = 0; j < 7; j++) if (d == j) v7[j] = -INFINITY;
            if (i == 0) m = bv;
            if (i < 64) { if (lane == i) { va = bv; ka = bk; } }
            else        { if (lane == i - 64) { vb2 = bv; kb = bk; } }
        }
        float ca = expf((va - m) * 10.f);
        float cb = (lane < K_ - 64) ? expf((vb2 - m) * 10.f) : 0.f;
        float ssum = ca + cb;
#pragma unroll
        for (int off = 1; off < 64; off <<= 1) ssum += __shfl_xor(ssum, off);
        float inv = 1.f / ssum;
        int qq = qj + 4 * w;
        int blo = max(0, 10 - qq), bhi = min(20, 105 - qq);
        {
            int a = ka / 21, b = ka - a * 21;
            int ae = min(max(a, alo), ahi), be = min(max(b, blo), bhi);
            yiw[w * 100 + lane] = ca * inv;
            pab[w * 100 + lane] = (ae << 8) | (be + 4 * w);
        }
        if (lane < K_ - 64) {
            int a = kb / 21, b = kb - a * 21;
            int ae = min(max(a, alo), ahi), be = min(max(b, blo), bhi);
            yiw[w * 100 + 64 + lane] = cb * inv;
            pab[w * 100 + 64 + lane] = (ae << 8) | (be + 4 * w);
        }
    } else {
        // restage B2 virtual window -> Wp half[27][32][16] (overlays Wh; score done)
        for (int pos = tid - 128; pos < 864; pos += 128) {
            int row = pos >> 5, col = pos & 31;
            int vr = min(max(qi - 10 + row, 0), 95);
            int vc = min(max(qj - 10 + col, 0), 95);
            const float* src = B2t + vr * 96 + vc;
            __half2 h2[8];
#pragma unroll
            for (int cc = 0; cc < 8; cc++)
                h2[cc] = __floats2half2_rn(src[(2 * cc) * HW_], src[(2 * cc + 1) * HW_]);
            *(int4*)(Wp + pos * 8)     = *(int4*)(h2);
            *(int4*)(Wp + pos * 8 + 4) = *(int4*)(h2 + 4);
        }
    }
    __syncthreads();

    // ---- PV: wave = (query, k-half); lane = (pi,pj); packed-f16 FMA; direct global atomics ----
    {
        int qv2 = w & 1, kh = w >> 1;
        if (lane < 49) {
            int pi = lane / 7, pj = lane - pi * 7;
            int rsel = lane & 1;                 // chunk rotation vs bank clusters
            __half2 z[8];
#pragma unroll
            for (int j = 0; j < 8; j++) z[j] = __float2half2_rn(0.f);
            int kb2 = kh * 50;
            for (int k = kb2; k < kb2 + 50; k++) {
                float y = yiw[qv2 * 100 + k];
                int pp = pab[qv2 * 100 + k];
                int row = (pp >> 8) + pi, col = (pp & 255) + pj;
                const __half2* cell = Wp + (row * 32 + col) * 8;
                int4 A0 = *(const int4*)(cell + rsel * 4);
                int4 A1 = *(const int4*)(cell + 4 - rsel * 4);
                const __half2* pa = (const __half2*)&A0;
                const __half2* pb2 = (const __half2*)&A1;
                __half2 yh = __float2half2_rn(y);
#pragma unroll
                for (int j = 0; j < 4; j++) {
                    z[j]     = __hfma2(pa[j],  yh, z[j]);
                    z[4 + j] = __hfma2(pb2[j], yh, z[4 + j]);
                }
            }
            int orow = min(qi + pi, 95), ocol = min(qj + 4 * qv2 + pj, 95);
            float* dst = ACCb + t * CI_ * HW_ + orow * 96 + ocol;
            int c0 = rsel * 8, c1 = 8 - c0;
#pragma unroll
            for (int jh = 0; jh < 4; jh++) {
                atomicAdd(dst + (c0 + 2 * jh) * HW_,     __low2float(z[jh]));
                atomicAdd(dst + (c0 + 2 * jh + 1) * HW_, __high2float(z[jh]));
                atomicAdd(dst + (c1 + 2 * jh) * HW_,     __low2float(z[4 + jh]));
                atomicAdd(dst + (c1 + 2 * jh + 1) * HW_, __high2float(z[4 + jh]));
            }
            if (t == 0 && kh == 0) atomicAdd(Zb + orow * 96 + ocol, 1.0f);
        }
    }
}

// ---------------- final: y = ACC/Z, conv1x1 + residual ----------------
template <int ISBF>
__device__ __forceinline__ void out_body(const void* vid, const float* w, const float* ACCb,
                                         const float* Zb, void* out, int t, int pix)
{
    float zv = Zb[pix];
    float y[CI_];
    int ab = t * CI_ * HW_ + pix;
#pragma unroll
    for (int ci = 0; ci < CI_; ci++) y[ci] = ACCb[ab + ci * HW_] / zv;
    int vb = t * C_ * HW_ + pix;
#pragma unroll 8
    for (int co = 0; co < C_; co++) {
        float s = w[1024 + co];
#pragma unroll
        for (int ci = 0; ci < CI_; ci++) s += w[co * CI_ + ci] * y[ci];
        float vv = ISBF ? ldbf(vid, vb + co * HW_) : ldf(vid, vb + co * HW_);
        float r = vv + s;
        if (ISBF) ((bf16*)out)[vb + co * HW_] = __float2bfloat16(r);
        else      ((float*)out)[vb + co * HW_] = r;
    }
}

__global__ __launch_bounds__(128) void out_k(const void* vid, const void* Ww, const void* Wb,
                                             const float* __restrict__ ACCb,
                                             const float* __restrict__ Zb, void* out)
{
    __shared__ float w[1088];
    __shared__ int sflag;
    int tid = threadIdx.x;
    int isbf = detect_flag(vid, tid, &sflag);
    if (isbf) { for (int i = tid; i < 1088; i += 128) w[i] = (i < 1024) ? ldbf(Ww, i) : ldbf(Wb, i - 1024); }
    else      { for (int i = tid; i < 1088; i += 128) w[i] = (i < 1024) ? ldf (Ww, i) : ldf (Wb, i - 1024); }
    __syncthreads();
    int p = blockIdx.x * 128 + tid;
    int t = p / HW_, pix = p - t * HW_;
    if (isbf) out_body<1>(vid, w, ACCb, Zb, out, t, pix);
    else      out_body<0>(vid, w, ACCb, Zb, out, t, pix);
}

extern "C" void kernel_launch(void* const* d_in, const int* in_sizes, int n_in,
                              void* d_out, int out_size, void* d_ws, size_t ws_size,
                              hipStream_t stream)
{
    // ws float layout: B1 @0, B2 @589824, B3 @1179648, ACC @1769472, Z @2359296
    float* ws   = (float*)d_ws;
    float* B1   = ws;
    float* B2   = ws + 589824;
    float* B3   = ws + 1179648;
    float* ACCb = ws + 1769472;
    float* Zb   = ws + 2359296;

    hipMemsetAsync(ACCb, 0, (589824 + 9216) * sizeof(float), stream);
    conv3_k<<<dim3(288), dim3(128), 0, stream>>>(d_in[0], d_in[1], d_in[2], d_in[3], d_in[4],
                                                 d_in[5], d_in[6], B1, B2, B3);
    attn_k<<<dim3(288, T_), dim3(256), 0, stream>>>(B1, B2, B3, ACCb, Zb);
    out_k<<<dim3(288), dim3(128), 0, stream>>>(d_in[0], d_in[7], d_in[8], ACCb, Zb, d_out);
}

// Round 4
// 231.556 us; speedup vs baseline: 2.2362x; 1.8446x over previous
//
#include <hip/hip_runtime.h>
#include <hip/hip_bf16.h>
#include <hip/hip_fp16.h>
#include <math.h>

typedef __hip_bfloat16 bf16;
typedef __attribute__((ext_vector_type(8))) short short8;
typedef __attribute__((ext_vector_type(4))) float float4v;

#define T_   4
#define C_   64
#define H_   96
#define W_   96
#define CI_  16
#define HW_  9216
#define NQ_  576
#define NC_  441
#define K_   100

__device__ __forceinline__ float ldbf(const void* p, int i) { return __bfloat162float(((const bf16*)p)[i]); }
__device__ __forceinline__ float ldf (const void* p, int i) { return ((const float*)p)[i]; }

__device__ __forceinline__ unsigned short f2bf(float x) {
    union { float f; unsigned u; } a; a.f = x;
    unsigned r = a.u + 0x7FFF + ((a.u >> 16) & 1);
    return (unsigned short)(r >> 16);
}
__device__ __forceinline__ float bf2f(unsigned short s) {
    union { unsigned u; float f; } a; a.u = ((unsigned)s) << 16;
    return a.f;
}
__device__ __forceinline__ unsigned okey(float f) {   // descending-order key
    unsigned u = __float_as_uint(f);
    return u ^ ((u & 0x80000000u) ? 0xFFFFFFFFu : 0x80000000u);
}

// per-block dtype vote (fp32 low-mantissa words decode to "insane" bf16 exponents)
__device__ __forceinline__ int detect_flag(const void* vid, int tid, int* sflag) {
    if (tid < 64) {
        unsigned short w = ((const unsigned short*)vid)[tid * 2];
        int e = (w >> 7) & 0xFF;
        int sane = ((e >= 100 && e <= 140) || ((w & 0x7FFF) == 0)) ? 1 : 0;
#pragma unroll
        for (int off = 1; off < 64; off <<= 1) sane += __shfl_xor(sane, off);
        if (tid == 0) *sflag = (sane >= 48) ? 1 : 0;
    }
    __syncthreads();
    return *sflag;
}

// ---------------- conv1x1 x3 ----------------
template <int ISBF>
__device__ __forceinline__ void conv3_body(const void* vid, const float* w, int t, int pix,
                                           float* B1, float* B2, float* B3)
{
    float a1[CI_], a2[CI_], a3[CI_];
#pragma unroll
    for (int o = 0; o < CI_; o++) { a1[o] = w[3072 + o]; a2[o] = w[3088 + o]; a3[o] = w[3104 + o]; }
    int base = t * C_ * HW_ + pix;
#pragma unroll 16
    for (int c = 0; c < C_; c++) {
        float v = ISBF ? ldbf(vid, base + c * HW_) : ldf(vid, base + c * HW_);
#pragma unroll
        for (int o = 0; o < CI_; o++) {
            a1[o] += v * w[o * 64 + c];
            a2[o] += v * w[1024 + o * 64 + c];
            a3[o] += v * w[2048 + o * 64 + c];
        }
    }
    int ob = t * CI_ * HW_ + pix;
#pragma unroll
    for (int o = 0; o < CI_; o++) {
        B1[ob + o * HW_] = a1[o];
        B2[ob + o * HW_] = a2[o];
        B3[ob + o * HW_] = a3[o];
    }
}

__global__ __launch_bounds__(128) void conv3_k(const void* vid, const void* gw, const void* gb,
                                               const void* tw, const void* tb, const void* pw,
                                               const void* pb,
                                               float* __restrict__ B1, float* __restrict__ B2,
                                               float* __restrict__ B3)
{
    __shared__ float w[3120];
    __shared__ int sflag;
    int tid = threadIdx.x;
    int isbf = detect_flag(vid, tid, &sflag);
    if (isbf) {
        for (int i = tid; i < 3120; i += 128) {
            float v;
            if (i < 1024) v = ldbf(gw, i);
            else if (i < 2048) v = ldbf(tw, i - 1024);
            else if (i < 3072) v = ldbf(pw, i - 2048);
            else if (i < 3088) v = ldbf(gb, i - 3072);
            else if (i < 3104) v = ldbf(tb, i - 3088);
            else v = ldbf(pb, i - 3104);
            w[i] = v;
        }
    } else {
        for (int i = tid; i < 3120; i += 128) {
            float v;
            if (i < 1024) v = ldf(gw, i);
            else if (i < 2048) v = ldf(tw, i - 1024);
            else if (i < 3072) v = ldf(pw, i - 2048);
            else if (i < 3088) v = ldf(gb, i - 3072);
            else if (i < 3104) v = ldf(tb, i - 3088);
            else v = ldf(pb, i - 3104);
            w[i] = v;
        }
    }
    __syncthreads();
    int p = blockIdx.x * 128 + tid;   // 288*128 = 36864 exactly
    int t = p / HW_, pix = p - t * HW_;
    if (isbf) conv3_body<1>(vid, w, t, pix, B1, B2, B3);
    else      conv3_body<0>(vid, w, t, pix, B1, B2, B3);
}

// ---------------- fused attention: one block = 2 horizontally-adjacent queries ----------------
// Single 28.7KB window plane, two-phase score (bf16 h then l, 3 MFMA terms total),
// parallel radix-threshold top-100 (exact; ties are border-duplicates = interchangeable),
// f16 PV with LDS kh-combine. LDS ~37 KB -> 4 blocks/CU.
__global__ __launch_bounds__(256, 4) void attn_k(const float* __restrict__ B1,
                                                 const float* __restrict__ B2,
                                                 const float* __restrict__ B3,
                                                 float* __restrict__ ACCb)
{
    __shared__ __align__(16) char SM[37136];
    short*   Win  = (short*)SM;                  // [28][32][16] one bf16 plane (h, then l, then f16 PV)
    float*   Sc   = (float*)(SM + 28672);        // [2][441]
    float*   Cb   = (float*)(SM + 32208);        // [4][16][16] score bounce (overlay)
    float*   yiw  = (float*)(SM + 32208);        // [2][100] (after score)
    int*     pab  = (int*)(SM + 33008);          // [2][100]
    __half2* Zc   = (__half2*)(SM + 33808);      // [2][49][8] PV combine
    int*     hist = (int*)(SM + 36944);          // [2][16]
    int*     ctl  = (int*)(SM + 37072);          // [2][4]: prefix, need, cgt, ctie
    float*   red  = (float*)(SM + 37104);        // [8]
    __half2* Wp   = (__half2*)SM;                // PV overlay [27][32][8] h2

    int tid = threadIdx.x;
    int p = blockIdx.x, t = blockIdx.y;
    int qy = p / 12, qxp = p - qy * 12;
    int qi = qy * 4, qj = qxp * 8;
    int alo = max(0, 10 - qi), ahi = min(20, 105 - qi);

    const float* B1t = B1 + t * CI_ * HW_;
    const float* B2t = B2 + t * CI_ * HW_;
    const float* B3t = B3 + t * CI_ * HW_;

    int lane = tid & 63, w = tid >> 6;
    int nn = lane & 15, qsel = nn >> 3, pjn = nn & 7;
    int koff = (lane >> 4) * 8;

    // ---- B-fragments (query patches) -> registers, bf16 h/l split ----
    short8 Bh[4], Bl[4];
    {
        int qjq = qj + 4 * qsel;
#pragma unroll
        for (int s = 0; s < 4; s++) {
#pragma unroll
            for (int j = 0; j < 8; j++) {
                int kk = s * 32 + koff + j;
                int pi = kk >> 4, c = kk & 15;
                float val = 0.f;
                if (pjn < 7 && pi < 7)
                    val = B1t[c * HW_ + min(qi + pi, 95) * 96 + min(qjq + pjn, 95)];
                unsigned short h = f2bf(val);
                Bh[s][j] = (short)h;
                Bl[s][j] = (short)f2bf(val - bf2f(h));
            }
        }
    }

    // ---- phase A: stage h-plane ----
    for (int pos = tid; pos < 864; pos += 256) {
        int row = pos >> 5, col = pos & 31;
        int vr = min(max(qi - 10 + row, 0), 95);
        int vc = min(max(qj - 10 + col, 0), 95);
        const float* src = B3t + vr * 96 + vc;
        short hs[16];
#pragma unroll
        for (int c = 0; c < 16; c++) hs[c] = (short)f2bf(src[c * HW_]);
        *(int4*)(Win + pos * 16)     = *(int4*)(hs);
        *(int4*)(Win + pos * 16 + 8) = *(int4*)(hs + 8);
    }
    for (int i = tid; i < 512; i += 256) Win[13824 + i] = 0;   // pad row 27
    __syncthreads();

    // ---- score phase A: acc = Ah*Bh + Ah*Bl ----
    {
        float* Cw = Cb + w * 256;
        for (int r = w; r < 21; r += 4) {
            float psum = 0.f;
            int v = (lane >= 21) ? 1 : 0;
            int b = lane - v * 21;
#pragma unroll
            for (int st = 0; st < 2; st++) {
                float4v acc = {0.f, 0.f, 0.f, 0.f};
#pragma unroll
                for (int s = 0; s < 4; s++) {
                    int arow = r + 2 * s + (lane >> 5);
                    int aoff = (arow * 32 + st * 16 + nn) * 16 + ((lane >> 4) & 1) * 8;
                    short8 A = *(const short8*)(Win + aoff);
                    acc = __builtin_amdgcn_mfma_f32_16x16x32_bf16(A, Bh[s], acc, 0, 0, 0);
                    acc = __builtin_amdgcn_mfma_f32_16x16x32_bf16(A, Bl[s], acc, 0, 0, 0);
                }
                *(float4v*)(Cw + nn * 16 + (lane >> 4) * 4) = acc;
                if (lane < 42) {
#pragma unroll
                    for (int pj = 0; pj < 7; pj++) {
                        int sp = b + 4 * v + pj;
                        if ((sp >> 4) == st) psum += Cw[(8 * v + pj) * 16 + (sp & 15)];
                    }
                }
            }
            if (lane < 42) Sc[v * 441 + r * 21 + b] = psum;
        }
    }
    __syncthreads();

    // ---- phase B: restage l-plane (L2-hot reload) ----
    for (int pos = tid; pos < 864; pos += 256) {
        int row = pos >> 5, col = pos & 31;
        int vr = min(max(qi - 10 + row, 0), 95);
        int vc = min(max(qj - 10 + col, 0), 95);
        const float* src = B3t + vr * 96 + vc;
        short ls[16];
#pragma unroll
        for (int c = 0; c < 16; c++) {
            float f = src[c * HW_];
            ls[c] = (short)f2bf(f - bf2f(f2bf(f)));
        }
        *(int4*)(Win + pos * 16)     = *(int4*)(ls);
        *(int4*)(Win + pos * 16 + 8) = *(int4*)(ls + 8);
    }
    for (int i = tid; i < 512; i += 256) Win[13824 + i] = 0;
    __syncthreads();

    // ---- score phase B: Sc += Al*Bh ----
    {
        float* Cw = Cb + w * 256;
        for (int r = w; r < 21; r += 4) {
            float psum = 0.f;
            int v = (lane >= 21) ? 1 : 0;
            int b = lane - v * 21;
#pragma unroll
            for (int st = 0; st < 2; st++) {
                float4v acc = {0.f, 0.f, 0.f, 0.f};
#pragma unroll
                for (int s = 0; s < 4; s++) {
                    int arow = r + 2 * s + (lane >> 5);
                    int aoff = (arow * 32 + st * 16 + nn) * 16 + ((lane >> 4) & 1) * 8;
                    short8 A = *(const short8*)(Win + aoff);
                    acc = __builtin_amdgcn_mfma_f32_16x16x32_bf16(A, Bh[s], acc, 0, 0, 0);
                }
                *(float4v*)(Cw + nn * 16 + (lane >> 4) * 4) = acc;
                if (lane < 42) {
#pragma unroll
                    for (int pj = 0; pj < 7; pj++) {
                        int sp = b + 4 * v + pj;
                        if ((sp >> 4) == st) psum += Cw[(8 * v + pj) * 16 + (sp & 15)];
                    }
                }
            }
            if (lane < 42) Sc[v * 441 + r * 21 + b] += psum;
        }
    }
    __syncthreads();

    // ---- fixup border duplicates (bitwise copies) + restage PV f16 plane + init topk ----
    for (int idx = tid; idx < 882; idx += 256) {
        int v = idx / 441, k = idx - v * 441;
        int a = k / 21, b = k - a * 21;
        int qq = qj + 4 * v;
        int blo = max(0, 10 - qq), bhi = min(20, 105 - qq);
        int ae = min(max(a, alo), ahi), be = min(max(b, blo), bhi);
        if (ae != a || be != b) Sc[v * 441 + k] = Sc[v * 441 + ae * 21 + be];
    }
    for (int pos = tid; pos < 864; pos += 256) {
        int row = pos >> 5, col = pos & 31;
        int vr = min(max(qi - 10 + row, 0), 95);
        int vc = min(max(qj - 10 + col, 0), 95);
        const float* src = B2t + vr * 96 + vc;
        __half2 h2[8];
#pragma unroll
        for (int cc = 0; cc < 8; cc++)
            h2[cc] = __floats2half2_rn(src[(2 * cc) * HW_], src[(2 * cc + 1) * HW_]);
        *(int4*)(Wp + pos * 8)     = *(int4*)(h2);
        *(int4*)(Wp + pos * 8 + 4) = *(int4*)(h2 + 4);
    }
    if (tid < 2) { ctl[tid * 4] = 0; ctl[tid * 4 + 1] = K_; ctl[tid * 4 + 2] = 0; ctl[tid * 4 + 3] = 0; }
    if (tid < 32) hist[tid] = 0;
    __syncthreads();

    // ---- parallel exact top-100 per query: radix-16 threshold search ----
    int g = tid >> 7, u = tid & 127;
    int wsel = (tid >> 6) & 1;
    unsigned kreg[4]; int ni = 0;
    for (int i = u; i < NC_; i += 128) kreg[ni++] = okey(Sc[g * 441 + i]);

#pragma unroll
    for (int ps = 7; ps >= 0; ps--) {
        unsigned pref = (unsigned)ctl[g * 4];
        for (int a = 0; a < ni; a++) {
            unsigned k = kreg[a];
            bool match = (ps == 7) ? true : ((k >> ((ps + 1) * 4)) == pref);
            if (match) atomicAdd(&hist[g * 16 + ((k >> (ps * 4)) & 15)], 1);
        }
        __syncthreads();
        if (u < 16) {
            int c = hist[g * 16 + u];
#pragma unroll
            for (int off = 1; off < 16; off <<= 1) {
                int o = __shfl_down(c, off);
                if (u + off < 16) c += o;
            }
            int nxt = __shfl_down(c, 1);
            if (u == 15) nxt = 0;
            int need = ctl[g * 4 + 1];
            if (c >= need && nxt < need) {
                ctl[g * 4]     = (ctl[g * 4] << 4) | (int)u;
                ctl[g * 4 + 1] = need - nxt;
            }
            hist[g * 16 + u] = 0;
        }
        __syncthreads();
    }

    // ---- selection (unordered; tie members are interchangeable duplicates) ----
    {
        unsigned theta = (unsigned)ctl[g * 4];
        int needF = ctl[g * 4 + 1];
        int base = K_ - needF;
        int qq = qj + 4 * g;
        int blo = max(0, 10 - qq), bhi = min(20, 105 - qq);
        int a2 = 0;
        for (int i = u; i < NC_; i += 128) {
            unsigned k = kreg[a2++];
            int slot = -1;
            if (k > theta) slot = atomicAdd(&ctl[g * 4 + 2], 1);
            else if (k == theta) {
                int j = atomicAdd(&ctl[g * 4 + 3], 1);
                if (j < needF) slot = base + j;
            }
            if (slot >= 0) {
                int a = i / 21, b = i - a * 21;
                int ae = min(max(a, alo), ahi), be = min(max(b, blo), bhi);
                yiw[g * 100 + slot] = Sc[g * 441 + i];
                pab[g * 100 + slot] = (ae << 8) | (be + 4 * g);
            }
        }
    }
    // max-reduce for softmax
    {
        float lm = -1e30f;
        for (int i = u; i < NC_; i += 128) lm = fmaxf(lm, Sc[g * 441 + i]);
#pragma unroll
        for (int off = 1; off < 64; off <<= 1) lm = fmaxf(lm, __shfl_xor(lm, off));
        if (lane == 0) red[g * 2 + wsel] = lm;
    }
    __syncthreads();
    {
        float m = fmaxf(red[g * 2], red[g * 2 + 1]);
        float wgt = (u < K_) ? expf((yiw[g * 100 + u] - m) * 10.f) : 0.f;
        float pssum = wgt;
#pragma unroll
        for (int off = 1; off < 64; off <<= 1) pssum += __shfl_xor(pssum, off);
        if (lane == 0) red[4 + g * 2 + wsel] = pssum;
        __syncthreads();
        float inv = 1.f / (red[4 + g * 2] + red[4 + g * 2 + 1]);
        if (u < K_) yiw[g * 100 + u] = wgt * inv;
    }
    __syncthreads();

    // ---- PV: wave = (query, k-half); f16 packed FMA; LDS kh-combine; atomics ----
    {
        int qv2 = w & 1, kh = w >> 1;
        __half2 z[8];
        int rsel = lane & 1;
        if (lane < 49) {
            int pi = lane / 7, pj = lane - pi * 7;
#pragma unroll
            for (int j = 0; j < 8; j++) z[j] = __float2half2_rn(0.f);
            int kb2 = kh * 50;
            for (int k = kb2; k < kb2 + 50; k++) {
                float y = yiw[qv2 * 100 + k];
                int pp = pab[qv2 * 100 + k];
                int row = (pp >> 8) + pi, col = (pp & 255) + pj;
                const __half2* cell = Wp + (row * 32 + col) * 8;
                int4 A0 = *(const int4*)(cell + rsel * 4);
                int4 A1 = *(const int4*)(cell + 4 - rsel * 4);
                const __half2* pa = (const __half2*)&A0;
                const __half2* pb2 = (const __half2*)&A1;
                __half2 yh = __float2half2_rn(y);
#pragma unroll
                for (int j = 0; j < 4; j++) {
                    z[j]     = __hfma2(pa[j],  yh, z[j]);
                    z[4 + j] = __hfma2(pb2[j], yh, z[4 + j]);
                }
            }
        }
        if (kh == 1 && lane < 49) {
            *(int4*)(Zc + (qv2 * 49 + lane) * 8)     = *(int4*)(z);
            *(int4*)(Zc + (qv2 * 49 + lane) * 8 + 4) = *(int4*)(z + 4);
        }
        __syncthreads();
        if (kh == 0 && lane < 49) {
            int pi = lane / 7, pj = lane - pi * 7;
            const __half2* zo = Zc + (qv2 * 49 + lane) * 8;
#pragma unroll
            for (int j = 0; j < 8; j++) z[j] = __hadd2(z[j], zo[j]);
            int orow = min(qi + pi, 95), ocol = min(qj + 4 * qv2 + pj, 95);
            float* dst = ACCb + t * CI_ * HW_ + orow * 96 + ocol;
            int c0 = rsel * 8, c1 = 8 - c0;
#pragma unroll
            for (int jh = 0; jh < 4; jh++) {
                atomicAdd(dst + (c0 + 2 * jh) * HW_,     __low2float(z[jh]));
                atomicAdd(dst + (c0 + 2 * jh + 1) * HW_, __high2float(z[jh]));
                atomicAdd(dst + (c1 + 2 * jh) * HW_,     __low2float(z[4 + jh]));
                atomicAdd(dst + (c1 + 2 * jh + 1) * HW_, __high2float(z[4 + jh]));
            }
        }
    }
}

// ---------------- final: y = ACC/Z (Z analytic), conv1x1 + residual ----------------
__device__ __forceinline__ int cntdim(int x) {
    int c = 0;
#pragma unroll
    for (int pp = 0; pp < 7; pp++) {
        int q = x - pp;
        c += (q >= 0 && q <= 92 && ((q & 3) == 0)) ? 1 : 0;
    }
    if (x == 95) c += 3;   // overhang q=92, p=4..6 clipped onto 95
    return c;
}

template <int ISBF>
__device__ __forceinline__ void out_body(const void* vid, const float* w, const float* ACCb,
                                         void* out, int t, int pix)
{
    int pi = pix / 96, pj = pix - pi * 96;
    float zv = (float)(cntdim(pi) * cntdim(pj));
    float invz = 1.f / zv;
    float y[CI_];
    int ab = t * CI_ * HW_ + pix;
#pragma unroll
    for (int ci = 0; ci < CI_; ci++) y[ci] = ACCb[ab + ci * HW_] * invz;
    int vb = t * C_ * HW_ + pix;
#pragma unroll 8
    for (int co = 0; co < C_; co++) {
        float s = w[1024 + co];
#pragma unroll
        for (int ci = 0; ci < CI_; ci++) s += w[co * CI_ + ci] * y[ci];
        float vv = ISBF ? ldbf(vid, vb + co * HW_) : ldf(vid, vb + co * HW_);
        float r = vv + s;
        if (ISBF) ((bf16*)out)[vb + co * HW_] = __float2bfloat16(r);
        else      ((float*)out)[vb + co * HW_] = r;
    }
}

__global__ __launch_bounds__(128) void out_k(const void* vid, const void* Ww, const void* Wb,
                                             const float* __restrict__ ACCb, void* out)
{
    __shared__ float w[1088];
    __shared__ int sflag;
    int tid = threadIdx.x;
    int isbf = detect_flag(vid, tid, &sflag);
    if (isbf) { for (int i = tid; i < 1088; i += 128) w[i] = (i < 1024) ? ldbf(Ww, i) : ldbf(Wb, i - 1024); }
    else      { for (int i = tid; i < 1088; i += 128) w[i] = (i < 1024) ? ldf (Ww, i) : ldf (Wb, i - 1024); }
    __syncthreads();
    int p = blockIdx.x * 128 + tid;
    int t = p / HW_, pix = p - t * HW_;
    if (isbf) out_body<1>(vid, w, ACCb, out, t, pix);
    else      out_body<0>(vid, w, ACCb, out, t, pix);
}

extern "C" void kernel_launch(void* const* d_in, const int* in_sizes, int n_in,
                              void* d_out, int out_size, void* d_ws, size_t ws_size,
                              hipStream_t stream)
{
    // ws float layout: B1 @0, B2 @589824, B3 @1179648, ACC @1769472
    float* ws   = (float*)d_ws;
    float* B1   = ws;
    float* B2   = ws + 589824;
    float* B3   = ws + 1179648;
    float* ACCb = ws + 1769472;

    hipMemsetAsync(ACCb, 0, 589824 * sizeof(float), stream);
    conv3_k<<<dim3(288), dim3(128), 0, stream>>>(d_in[0], d_in[1], d_in[2], d_in[3], d_in[4],
                                                 d_in[5], d_in[6], B1, B2, B3);
    attn_k<<<dim3(288, T_), dim3(256), 0, stream>>>(B1, B2, B3, ACCb);
    out_k<<<dim3(288), dim3(128), 0, stream>>>(d_in[0], d_in[7], d_in[8], ACCb, d_out);
}